// Round 4
// baseline (422.774 us; speedup 1.0000x reference)
//
#include <hip/hip_runtime.h>

using u16 = unsigned short;
using u32 = unsigned int;

#define M_NODES 50000
#define E_EDGES 600000
#define EPS_BN 1e-5f
#define BKT 48

typedef __attribute__((ext_vector_type(8))) short bf16x8;
typedef __attribute__((ext_vector_type(4))) float f32x4;

__device__ __forceinline__ float bf2f(u16 v) {
  union { u32 u; float f; } x; x.u = ((u32)v) << 16; return x.f;
}
__device__ __forceinline__ float lo16f(u32 v) {
  union { u32 u; float f; } x; x.u = v << 16; return x.f;
}
__device__ __forceinline__ float hi16f(u32 v) {
  union { u32 u; float f; } x; x.u = v & 0xffff0000u; return x.f;
}
__device__ __forceinline__ u16 f2bf(float f) {
  union { float f; u32 u; } x; x.f = f;
  u32 r = x.u + 0x7fffu + ((x.u >> 16) & 1u);
  return (u16)(r >> 16);
}

// ---------------- bucket build ----------------
__global__ void k_place(const int* __restrict__ src, const int* __restrict__ dst,
                        int* __restrict__ cnt, int* __restrict__ bucket, int n) {
  int e = blockIdx.x * blockDim.x + threadIdx.x;
  if (e < n) {
    int d = dst[e];
    int p = atomicAdd(&cnt[d], 1);
    if (p < BKT) bucket[d * BKT + p] = src[e];
  }
}

// ---------------- weight prep: fp32 -> bf16 packed ----------------
__global__ __launch_bounds__(256) void k_prep(const float* __restrict__ encW2,
                                              const float* __restrict__ Wl,
                                              const float* __restrict__ Wr,
                                              const float* __restrict__ decW1,
                                              u16* __restrict__ Bp) {
  int e = blockIdx.x * 256 + threadIdx.x;
  float v;
  if (e < 32768) {
    v = encW2[e];
  } else if (e < 196608) {
    int r = e - 32768;
    int i = r >> 15;
    int rr = r & 32767;
    int n = rr >> 8;
    int k = rr & 255;
    v = (k < 128) ? Wl[i * 16384 + n * 128 + k] : Wr[i * 16384 + n * 128 + (k - 128)];
  } else {
    v = decW1[e - 196608];
  }
  Bp[e] = f2bf(v);
}

// ---------------- output init: out[n][o] = b2[o] ----------------
__global__ void k_outinit(float* __restrict__ out, const float* __restrict__ b2, int n4) {
  int i = blockIdx.x * 256 + threadIdx.x;
  if (i < n4) out[i] = b2[i & 3];
}

// ---------------- fused mean-aggregation (+BN+relu of previous layer) ----------------
// TRANS=0: mean of raw z.  TRANS=1: mean of relu(s*z+t) and z'[node]=relu(s*z[node]+t),
// with s,t recomputed per block from ssum (sum, sumsq over M rows).
template <int TRANS>
__global__ __launch_bounds__(256) void k_agg(const u16* __restrict__ z,
                                             const int* __restrict__ cnt,
                                             const int* __restrict__ bucket,
                                             const float* __restrict__ ssum,
                                             const float* __restrict__ gamma,
                                             const float* __restrict__ beta,
                                             u16* __restrict__ mean,
                                             u16* __restrict__ zp, int M) {
  __shared__ float s_sc[256];
  int t = threadIdx.x;
  if (TRANS) {
    if (t < 128) {
      float m = ssum[t] * (1.0f / M_NODES);
      float var = ssum[128 + t] * (1.0f / M_NODES) - m * m;
      float s = gamma[t] * rsqrtf(var + EPS_BN);
      s_sc[t] = s;
      s_sc[128 + t] = beta[t] - m * s;
    }
    __syncthreads();
  }
  int node = blockIdx.x * 4 + (t >> 6);
  int lane = t & 63;
  int slot = lane >> 4;
  int fc = lane & 15;
  float sreg[8], treg[8];
  if (TRANS) {
    #pragma unroll
    for (int i = 0; i < 8; ++i) { sreg[i] = s_sc[fc * 8 + i]; treg[i] = s_sc[128 + fc * 8 + i]; }
  }
  int deg = cnt[node];
  int nd = deg < BKT ? deg : BKT;
  const int* bk = bucket + (size_t)node * BKT;
  float a[8] = {};
  for (int j = slot; j < nd; j += 4) {
    int s = bk[j];
    uint4 v = *(const uint4*)(z + (size_t)s * 128 + fc * 8);
    float f[8] = {lo16f(v.x), hi16f(v.x), lo16f(v.y), hi16f(v.y),
                  lo16f(v.z), hi16f(v.z), lo16f(v.w), hi16f(v.w)};
    #pragma unroll
    for (int i = 0; i < 8; ++i) {
      float vv = TRANS ? fmaxf(fmaf(f[i], sreg[i], treg[i]), 0.f) : f[i];
      a[i] += vv;
    }
  }
  #pragma unroll
  for (int i = 0; i < 8; ++i) {
    a[i] += __shfl_xor(a[i], 16, 64);
    a[i] += __shfl_xor(a[i], 32, 64);
  }
  if (slot == 0) {
    float inv = 1.0f / (float)(deg > 1 ? deg : 1);
    uint4 r;
    r.x = (u32)f2bf(a[0] * inv) | ((u32)f2bf(a[1] * inv) << 16);
    r.y = (u32)f2bf(a[2] * inv) | ((u32)f2bf(a[3] * inv) << 16);
    r.z = (u32)f2bf(a[4] * inv) | ((u32)f2bf(a[5] * inv) << 16);
    r.w = (u32)f2bf(a[6] * inv) | ((u32)f2bf(a[7] * inv) << 16);
    *(uint4*)(mean + (size_t)node * 128 + fc * 8) = r;
  }
  if (TRANS && slot == 1) {
    uint4 v = *(const uint4*)(z + (size_t)node * 128 + fc * 8);
    float f[8] = {lo16f(v.x), hi16f(v.x), lo16f(v.y), hi16f(v.y),
                  lo16f(v.z), hi16f(v.z), lo16f(v.w), hi16f(v.w)};
    u16 o[8];
    #pragma unroll
    for (int i = 0; i < 8; ++i) o[i] = f2bf(fmaxf(fmaf(f[i], sreg[i], treg[i]), 0.f));
    uint4 r;
    r.x = (u32)o[0] | ((u32)o[1] << 16);
    r.y = (u32)o[2] | ((u32)o[3] << 16);
    r.z = (u32)o[4] | ((u32)o[5] << 16);
    r.w = (u32)o[6] | ((u32)o[7] << 16);
    *(uint4*)(zp + (size_t)node * 128 + fc * 8) = r;
  }
}

// ---------------- encoder layer 1 ----------------
__global__ __launch_bounds__(256) void k_enc1(const float* __restrict__ x,
                                              const float* __restrict__ W1,
                                              const float* __restrict__ b1,
                                              u16* __restrict__ h, int M) {
  __shared__ float Ws[256 * 7];
  __shared__ float xs[8 * 7];
  int t = threadIdx.x;
  for (int i = t; i < 256 * 7; i += 256) Ws[i] = W1[i];
  int m0 = blockIdx.x * 8;
  if (t < 56) xs[t] = x[(size_t)m0 * 7 + t];
  __syncthreads();
  float bj = b1[t];
  float wreg[7];
  #pragma unroll
  for (int k = 0; k < 7; ++k) wreg[k] = Ws[t * 7 + k];
  #pragma unroll
  for (int i = 0; i < 8; ++i) {
    float acc = bj;
    #pragma unroll
    for (int k = 0; k < 7; ++k) acc = fmaf(wreg[k], xs[i * 7 + k], acc);
    h[(size_t)(m0 + i) * 256 + t] = f2bf(fmaxf(acc, 0.f));
  }
}

// ---------------- bf16 MFMA GEMM, BM=64 x BN=128 ----------------
// DO_STATS: accumulate column sum/sumsq into ssum (for next layer's BN).
// DEC: no C store; instead h=relu(v+bias), out[row][o] += h . W2[o][ncols] (atomicAdd).
#define GLOAD_LDS16(g, l)                                                        \
  __builtin_amdgcn_global_load_lds((const __attribute__((address_space(1))) void*)(g), \
                                   (__attribute__((address_space(3))) void*)(l), 16, 0, 0)

template <int KSTEPS, int DO_STATS, int DEC>
__global__ __launch_bounds__(256) void k_mfma_gemm(
    const u16* __restrict__ A1, const u16* __restrict__ A2, int strideA,
    const u16* __restrict__ Bp, const float* __restrict__ bias,
    u16* __restrict__ C, int ldc, int M, int relu, float* __restrict__ ssum,
    const float* __restrict__ W2, float* __restrict__ outp) {
  constexpr int KHALF = KSTEPS / 2;
  __shared__ __align__(16) u16 As[2][2048];
  __shared__ __align__(16) u16 Bs[2][4096];
  __shared__ float bnbuf[256];
  int t = threadIdx.x;
  int lane = t & 63;
  int w = t >> 6;
  int m0 = blockIdx.x * 64;
  int n0 = blockIdx.y * 128;
  if (DO_STATS) bnbuf[t] = 0.f;

  f32x4 acc[2][4] = {};

  auto stage = [&](int kt, int b) {
    {
      int s = w * 64 + lane;
      int row = s >> 2;
      int cc = (s & 3) ^ ((row >> 1) & 3);
      int rg = m0 + row;
      rg = rg < M ? rg : M - 1;
      const u16* src = (kt < KHALF ? A1 : A2) + (size_t)rg * strideA + (kt % KHALF) * 32 + cc * 8;
      GLOAD_LDS16(src, &As[b][w * 512]);
    }
    #pragma unroll
    for (int j = 0; j < 2; ++j) {
      int s = (w * 2 + j) * 64 + lane;
      int row = s >> 2;
      int cc = (s & 3) ^ ((row >> 1) & 3);
      const u16* src = Bp + (size_t)(n0 + row) * (KSTEPS * 32) + kt * 32 + cc * 8;
      GLOAD_LDS16(src, &Bs[b][(w * 2 + j) * 512]);
    }
  };

  stage(0, 0);
  #pragma unroll
  for (int kt = 0; kt < KSTEPS; ++kt) {
    const int b = kt & 1;
    if (kt + 1 < KSTEPS) {
      stage(kt + 1, (kt + 1) & 1);
      asm volatile("s_waitcnt vmcnt(3)" ::: "memory");
    } else {
      asm volatile("s_waitcnt vmcnt(0)" ::: "memory");
    }
    __builtin_amdgcn_s_barrier();
    asm volatile("" ::: "memory");

    bf16x8 af[2], bfr[4];
    int c16 = lane >> 4;
    #pragma unroll
    for (int mf = 0; mf < 2; ++mf) {
      int row = (w & 1) * 32 + mf * 16 + (lane & 15);
      int cs = c16 ^ ((row >> 1) & 3);
      af[mf] = *(const bf16x8*)&As[b][row * 32 + cs * 8];
    }
    #pragma unroll
    for (int nf = 0; nf < 4; ++nf) {
      int row = (w >> 1) * 64 + nf * 16 + (lane & 15);
      int cs = c16 ^ ((row >> 1) & 3);
      bfr[nf] = *(const bf16x8*)&Bs[b][row * 32 + cs * 8];
    }
    #pragma unroll
    for (int mf = 0; mf < 2; ++mf)
      #pragma unroll
      for (int nf = 0; nf < 4; ++nf)
        acc[mf][nf] = __builtin_amdgcn_mfma_f32_16x16x32_bf16(af[mf], bfr[nf], acc[mf][nf], 0, 0, 0);

    asm volatile("s_waitcnt lgkmcnt(0)" ::: "memory");
    __builtin_amdgcn_sched_barrier(0);
    __builtin_amdgcn_s_barrier();
    asm volatile("" ::: "memory");
  }

  int c16 = lane >> 4;
  float breg[4];
  #pragma unroll
  for (int nf = 0; nf < 4; ++nf)
    breg[nf] = bias[n0 + (w >> 1) * 64 + nf * 16 + (lane & 15)];

  if (DEC) {
    float w2reg[4][4];
    #pragma unroll
    for (int o = 0; o < 4; ++o)
      #pragma unroll
      for (int nf = 0; nf < 4; ++nf)
        w2reg[o][nf] = W2[o * 256 + n0 + (w >> 1) * 64 + nf * 16 + (lane & 15)];
    #pragma unroll
    for (int mf = 0; mf < 2; ++mf) {
      #pragma unroll
      for (int j = 0; j < 4; ++j) {
        int rl = (w & 1) * 32 + mf * 16 + c16 * 4 + j;
        int rg = m0 + rl;
        float v[4];
        #pragma unroll
        for (int nf = 0; nf < 4; ++nf) v[nf] = fmaxf(acc[mf][nf][j] + breg[nf], 0.f);
        #pragma unroll
        for (int o = 0; o < 4; ++o) {
          float pv = v[0] * w2reg[o][0] + v[1] * w2reg[o][1] + v[2] * w2reg[o][2] + v[3] * w2reg[o][3];
          pv += __shfl_xor(pv, 1, 16);
          pv += __shfl_xor(pv, 2, 16);
          pv += __shfl_xor(pv, 4, 16);
          pv += __shfl_xor(pv, 8, 16);
          if ((lane & 15) == 0 && rg < M) atomicAdd(outp + (size_t)rg * 4 + o, pv);
        }
      }
    }
    return;
  }

  float cs_[4] = {}, cq_[4] = {};
  #pragma unroll
  for (int mf = 0; mf < 2; ++mf) {
    #pragma unroll
    for (int j = 0; j < 4; ++j) {
      int rl = (w & 1) * 32 + mf * 16 + c16 * 4 + j;
      int rg = m0 + rl;
      if (rg < M) {
        #pragma unroll
        for (int nf = 0; nf < 4; ++nf) {
          int cl = (w >> 1) * 64 + nf * 16 + (lane & 15);
          float v = acc[mf][nf][j] + breg[nf];
          if (relu) v = fmaxf(v, 0.f);
          C[(size_t)rg * ldc + n0 + cl] = f2bf(v);
          if (DO_STATS) { cs_[nf] += v; cq_[nf] = fmaf(v, v, cq_[nf]); }
        }
      }
    }
  }

  if (DO_STATS) {
    #pragma unroll
    for (int nf = 0; nf < 4; ++nf) {
      float s = cs_[nf], q = cq_[nf];
      s += __shfl_xor(s, 16, 64); s += __shfl_xor(s, 32, 64);
      q += __shfl_xor(q, 16, 64); q += __shfl_xor(q, 32, 64);
      if (c16 == 0) {
        int cl = (w >> 1) * 64 + nf * 16 + (lane & 15);
        atomicAdd(&bnbuf[cl], s);
        atomicAdd(&bnbuf[128 + cl], q);
      }
    }
    __syncthreads();
    atomicAdd(&ssum[t], bnbuf[t]);
  }
}

// ---------------- launch ----------------
extern "C" void kernel_launch(void* const* d_in, const int* in_sizes, int n_in,
                              void* d_out, int out_size, void* d_ws, size_t ws_size,
                              hipStream_t stream) {
  const float* x     = (const float*)d_in[0];
  const int*   ei    = (const int*)d_in[1];
  const float* encW1 = (const float*)d_in[2];
  const float* encb1 = (const float*)d_in[3];
  const float* encW2 = (const float*)d_in[4];
  const float* encb2 = (const float*)d_in[5];
  const float* Wl    = (const float*)d_in[6];
  const float* bl    = (const float*)d_in[7];
  const float* Wr    = (const float*)d_in[8];
  const float* gamma = (const float*)d_in[9];
  const float* beta  = (const float*)d_in[10];
  const float* decW1 = (const float*)d_in[11];
  const float* decb1 = (const float*)d_in[12];
  const float* decW2 = (const float*)d_in[13];
  const float* decb2 = (const float*)d_in[14];
  float* out = (float*)d_out;

  const int M = M_NODES, E = E_EDGES;
  char* p = (char*)d_ws;
  auto take = [&](size_t b) { char* r = p; p += (b + 255) & ~(size_t)255; return r; };
  u16* zA     = (u16*)take((size_t)M * 128 * 2);
  u16* zB     = (u16*)take((size_t)M * 128 * 2);
  u16* zP     = (u16*)take((size_t)M * 128 * 2);
  u16* mean   = (u16*)take((size_t)M * 128 * 2);
  u16* hbuf   = (u16*)take((size_t)M * 256 * 2);
  u16* Bpack  = (u16*)take((size_t)229376 * 2);
  int* cnt    = (int*)take((size_t)M * 4);
  int* bucket = (int*)take((size_t)M * BKT * 4);
  float* ssums = (float*)take(4 * 256 * 4);

  const int* srcp = ei;
  const int* dstp = ei + E;

  k_prep<<<896, 256, 0, stream>>>(encW2, Wl, Wr, decW1, Bpack);
  hipMemsetAsync(cnt, 0, (size_t)M * 4, stream);
  hipMemsetAsync(ssums, 0, 4 * 256 * 4, stream);
  k_outinit<<<(M * 4 + 255) / 256, 256, 0, stream>>>(out, decb2, M * 4);
  k_place<<<(E + 255) / 256, 256, 0, stream>>>(srcp, dstp, cnt, bucket, E);

  const int GX = (M + 63) / 64;

  // encoder
  k_enc1<<<M / 8, 256, 0, stream>>>(x, encW1, encb1, hbuf, M);
  k_mfma_gemm<8, 0, 0><<<dim3(GX, 1), 256, 0, stream>>>(
      hbuf, hbuf + 128, 256, Bpack, encb2, zA, 128, M, 0, nullptr, nullptr, nullptr);

  u16* cur = zA;
  u16* nxt = zB;
  for (int i = 0; i < 5; ++i) {
    if (i == 0) {
      k_agg<0><<<M / 4, 256, 0, stream>>>(cur, cnt, bucket, nullptr, nullptr, nullptr,
                                          mean, zP, M);
    } else {
      k_agg<1><<<M / 4, 256, 0, stream>>>(cur, cnt, bucket, ssums + (i - 1) * 256,
                                          gamma + (size_t)(i - 1) * 128,
                                          beta + (size_t)(i - 1) * 128, mean, zP, M);
    }
    const u16* A2 = (i == 0) ? cur : zP;
    if (i < 4) {
      k_mfma_gemm<8, 1, 0><<<dim3(GX, 1), 256, 0, stream>>>(
          mean, A2, 128, Bpack + 32768 + i * 32768, bl + (size_t)i * 128,
          nxt, 128, M, 0, ssums + i * 256, nullptr, nullptr);
    } else {
      k_mfma_gemm<8, 0, 0><<<dim3(GX, 1), 256, 0, stream>>>(
          mean, A2, 128, Bpack + 32768 + i * 32768, bl + (size_t)i * 128,
          nxt, 128, M, 0, nullptr, nullptr, nullptr);
    }
    u16* tswap = cur; cur = nxt; nxt = tswap;
  }

  // decoder: layer1 GEMM with fused relu + layer2 dot + atomic accumulate
  k_mfma_gemm<4, 0, 1><<<dim3(GX, 2), 256, 0, stream>>>(
      cur, cur + 64, 128, Bpack + 196608, decb1, nullptr, 0, M, 1, nullptr,
      decW2, out);
}

// Round 5
// 404.401 us; speedup vs baseline: 1.0454x; 1.0454x over previous
//
#include <hip/hip_runtime.h>

using u16 = unsigned short;
using u32 = unsigned int;

#define M_NODES 50000
#define E_EDGES 600000
#define EPS_BN 1e-5f
#define BKT 48

typedef __attribute__((ext_vector_type(8))) short bf16x8;
typedef __attribute__((ext_vector_type(4))) float f32x4;

__device__ __forceinline__ float bf2f(u16 v) {
  union { u32 u; float f; } x; x.u = ((u32)v) << 16; return x.f;
}
__device__ __forceinline__ float lo16f(u32 v) {
  union { u32 u; float f; } x; x.u = v << 16; return x.f;
}
__device__ __forceinline__ float hi16f(u32 v) {
  union { u32 u; float f; } x; x.u = v & 0xffff0000u; return x.f;
}
__device__ __forceinline__ u16 f2bf(float f) {
  union { float f; u32 u; } x; x.f = f;
  u32 r = x.u + 0x7fffu + ((x.u >> 16) & 1u);
  return (u16)(r >> 16);
}

// ---------------- bucket build ----------------
__global__ void k_place(const int* __restrict__ src, const int* __restrict__ dst,
                        int* __restrict__ cnt, int* __restrict__ bucket, int n) {
  int e = blockIdx.x * blockDim.x + threadIdx.x;
  if (e < n) {
    int d = dst[e];
    int p = atomicAdd(&cnt[d], 1);
    if (p < BKT) bucket[d * BKT + p] = src[e];
  }
}

// ---------------- weight prep: fp32 -> bf16 packed ----------------
__global__ __launch_bounds__(256) void k_prep(const float* __restrict__ encW2,
                                              const float* __restrict__ Wl,
                                              const float* __restrict__ Wr,
                                              const float* __restrict__ decW1,
                                              u16* __restrict__ Bp) {
  int e = blockIdx.x * 256 + threadIdx.x;
  float v;
  if (e < 32768) {
    v = encW2[e];
  } else if (e < 196608) {
    int r = e - 32768;
    int i = r >> 15;
    int rr = r & 32767;
    int n = rr >> 8;
    int k = rr & 255;
    v = (k < 128) ? Wl[i * 16384 + n * 128 + k] : Wr[i * 16384 + n * 128 + (k - 128)];
  } else {
    v = decW1[e - 196608];
  }
  Bp[e] = f2bf(v);
}

// ---------------- fused mean-aggregation (+BN+relu of previous layer) ----------------
template <int TRANS>
__global__ __launch_bounds__(256) void k_agg(const u16* __restrict__ z,
                                             const int* __restrict__ cnt,
                                             const int* __restrict__ bucket,
                                             const float* __restrict__ ssum,
                                             const float* __restrict__ gamma,
                                             const float* __restrict__ beta,
                                             u16* __restrict__ mean,
                                             u16* __restrict__ zp, int M) {
  __shared__ float s_sc[256];
  int t = threadIdx.x;
  if (TRANS) {
    if (t < 128) {
      float m = ssum[t] * (1.0f / M_NODES);
      float var = ssum[128 + t] * (1.0f / M_NODES) - m * m;
      float s = gamma[t] * rsqrtf(var + EPS_BN);
      s_sc[t] = s;
      s_sc[128 + t] = beta[t] - m * s;
    }
    __syncthreads();
  }
  int node = blockIdx.x * 4 + (t >> 6);
  int lane = t & 63;
  int slot = lane >> 4;
  int fc = lane & 15;
  float sreg[8], treg[8];
  if (TRANS) {
    #pragma unroll
    for (int i = 0; i < 8; ++i) { sreg[i] = s_sc[fc * 8 + i]; treg[i] = s_sc[128 + fc * 8 + i]; }
  }
  int deg = cnt[node];
  int nd = deg < BKT ? deg : BKT;
  const int* bk = bucket + (size_t)node * BKT;
  float a[8] = {};
  for (int j = slot; j < nd; j += 4) {
    int s = bk[j];
    uint4 v = *(const uint4*)(z + (size_t)s * 128 + fc * 8);
    float f[8] = {lo16f(v.x), hi16f(v.x), lo16f(v.y), hi16f(v.y),
                  lo16f(v.z), hi16f(v.z), lo16f(v.w), hi16f(v.w)};
    #pragma unroll
    for (int i = 0; i < 8; ++i) {
      float vv = TRANS ? fmaxf(fmaf(f[i], sreg[i], treg[i]), 0.f) : f[i];
      a[i] += vv;
    }
  }
  #pragma unroll
  for (int i = 0; i < 8; ++i) {
    a[i] += __shfl_xor(a[i], 16, 64);
    a[i] += __shfl_xor(a[i], 32, 64);
  }
  if (slot == 0) {
    float inv = 1.0f / (float)(deg > 1 ? deg : 1);
    uint4 r;
    r.x = (u32)f2bf(a[0] * inv) | ((u32)f2bf(a[1] * inv) << 16);
    r.y = (u32)f2bf(a[2] * inv) | ((u32)f2bf(a[3] * inv) << 16);
    r.z = (u32)f2bf(a[4] * inv) | ((u32)f2bf(a[5] * inv) << 16);
    r.w = (u32)f2bf(a[6] * inv) | ((u32)f2bf(a[7] * inv) << 16);
    *(uint4*)(mean + (size_t)node * 128 + fc * 8) = r;
  }
  if (TRANS && slot == 1) {
    uint4 v = *(const uint4*)(z + (size_t)node * 128 + fc * 8);
    float f[8] = {lo16f(v.x), hi16f(v.x), lo16f(v.y), hi16f(v.y),
                  lo16f(v.z), hi16f(v.z), lo16f(v.w), hi16f(v.w)};
    u16 o[8];
    #pragma unroll
    for (int i = 0; i < 8; ++i) o[i] = f2bf(fmaxf(fmaf(f[i], sreg[i], treg[i]), 0.f));
    uint4 r;
    r.x = (u32)o[0] | ((u32)o[1] << 16);
    r.y = (u32)o[2] | ((u32)o[3] << 16);
    r.z = (u32)o[4] | ((u32)o[5] << 16);
    r.w = (u32)o[6] | ((u32)o[7] << 16);
    *(uint4*)(zp + (size_t)node * 128 + fc * 8) = r;
  }
}

// ---------------- encoder layer 1 ----------------
__global__ __launch_bounds__(256) void k_enc1(const float* __restrict__ x,
                                              const float* __restrict__ W1,
                                              const float* __restrict__ b1,
                                              u16* __restrict__ h, int M) {
  __shared__ float Ws[256 * 7];
  __shared__ float xs[8 * 7];
  int t = threadIdx.x;
  for (int i = t; i < 256 * 7; i += 256) Ws[i] = W1[i];
  int m0 = blockIdx.x * 8;
  if (t < 56) xs[t] = x[(size_t)m0 * 7 + t];
  __syncthreads();
  float bj = b1[t];
  float wreg[7];
  #pragma unroll
  for (int k = 0; k < 7; ++k) wreg[k] = Ws[t * 7 + k];
  #pragma unroll
  for (int i = 0; i < 8; ++i) {
    float acc = bj;
    #pragma unroll
    for (int k = 0; k < 7; ++k) acc = fmaf(wreg[k], xs[i * 7 + k], acc);
    h[(size_t)(m0 + i) * 256 + t] = f2bf(fmaxf(acc, 0.f));
  }
}

// ---------------- bf16 MFMA GEMM, BM=64 x BN=128, plain single-barrier dbuf ----------------
#define GLOAD_LDS16(g, l)                                                        \
  __builtin_amdgcn_global_load_lds((const __attribute__((address_space(1))) void*)(g), \
                                   (__attribute__((address_space(3))) void*)(l), 16, 0, 0)

template <int KSTEPS, int DO_STATS>
__global__ __launch_bounds__(256) void k_mfma_gemm(
    const u16* __restrict__ A1, const u16* __restrict__ A2, int strideA,
    const u16* __restrict__ Bp, const float* __restrict__ bias,
    u16* __restrict__ C, int ldc, int M, int relu, float* __restrict__ ssum) {
  constexpr int KHALF = KSTEPS / 2;
  __shared__ __align__(16) u16 As[2][2048];
  __shared__ __align__(16) u16 Bs[2][4096];
  __shared__ float bnbuf[256];
  int t = threadIdx.x;
  int lane = t & 63;
  int w = t >> 6;
  int m0 = blockIdx.x * 64;
  int n0 = blockIdx.y * 128;
  if (DO_STATS) bnbuf[t] = 0.f;

  f32x4 acc[2][4] = {};

  auto stage = [&](int kt, int b) {
    {
      int s = w * 64 + lane;
      int row = s >> 2;
      int cc = (s & 3) ^ ((row >> 1) & 3);
      int rg = m0 + row;
      rg = rg < M ? rg : M - 1;
      const u16* src = (kt < KHALF ? A1 : A2) + (size_t)rg * strideA + (kt % KHALF) * 32 + cc * 8;
      GLOAD_LDS16(src, &As[b][w * 512]);
    }
    #pragma unroll
    for (int j = 0; j < 2; ++j) {
      int s = (w * 2 + j) * 64 + lane;
      int row = s >> 2;
      int cc = (s & 3) ^ ((row >> 1) & 3);
      const u16* src = Bp + (size_t)(n0 + row) * (KSTEPS * 32) + kt * 32 + cc * 8;
      GLOAD_LDS16(src, &Bs[b][(w * 2 + j) * 512]);
    }
  };

  stage(0, 0);
  __syncthreads();
  #pragma unroll
  for (int kt = 0; kt < KSTEPS; ++kt) {
    const int b = kt & 1;
    if (kt + 1 < KSTEPS) stage(kt + 1, (kt + 1) & 1);

    bf16x8 af[2], bfr[4];
    int c16 = lane >> 4;
    #pragma unroll
    for (int mf = 0; mf < 2; ++mf) {
      int row = (w & 1) * 32 + mf * 16 + (lane & 15);
      int cs = c16 ^ ((row >> 1) & 3);
      af[mf] = *(const bf16x8*)&As[b][row * 32 + cs * 8];
    }
    #pragma unroll
    for (int nf = 0; nf < 4; ++nf) {
      int row = (w >> 1) * 64 + nf * 16 + (lane & 15);
      int cs = c16 ^ ((row >> 1) & 3);
      bfr[nf] = *(const bf16x8*)&Bs[b][row * 32 + cs * 8];
    }
    #pragma unroll
    for (int mf = 0; mf < 2; ++mf)
      #pragma unroll
      for (int nf = 0; nf < 4; ++nf)
        acc[mf][nf] = __builtin_amdgcn_mfma_f32_16x16x32_bf16(af[mf], bfr[nf], acc[mf][nf], 0, 0, 0);

    __syncthreads();
  }

  int c16 = lane >> 4;
  float breg[4];
  #pragma unroll
  for (int nf = 0; nf < 4; ++nf)
    breg[nf] = bias[n0 + (w >> 1) * 64 + nf * 16 + (lane & 15)];

  float cs_[4] = {}, cq_[4] = {};
  #pragma unroll
  for (int mf = 0; mf < 2; ++mf) {
    #pragma unroll
    for (int j = 0; j < 4; ++j) {
      int rl = (w & 1) * 32 + mf * 16 + c16 * 4 + j;
      int rg = m0 + rl;
      if (rg < M) {
        #pragma unroll
        for (int nf = 0; nf < 4; ++nf) {
          int cl = (w >> 1) * 64 + nf * 16 + (lane & 15);
          float v = acc[mf][nf][j] + breg[nf];
          if (relu) v = fmaxf(v, 0.f);
          C[(size_t)rg * ldc + n0 + cl] = f2bf(v);
          if (DO_STATS) { cs_[nf] += v; cq_[nf] = fmaf(v, v, cq_[nf]); }
        }
      }
    }
  }

  if (DO_STATS) {
    #pragma unroll
    for (int nf = 0; nf < 4; ++nf) {
      float s = cs_[nf], q = cq_[nf];
      s += __shfl_xor(s, 16, 64); s += __shfl_xor(s, 32, 64);
      q += __shfl_xor(q, 16, 64); q += __shfl_xor(q, 32, 64);
      if (c16 == 0) {
        int cl = (w >> 1) * 64 + nf * 16 + (lane & 15);
        atomicAdd(&bnbuf[cl], s);
        atomicAdd(&bnbuf[128 + cl], q);
      }
    }
    __syncthreads();
    atomicAdd(&ssum[t], bnbuf[t]);
  }
}

// ---------------- decoder layer 2: N=4, K=256, bf16 in ----------------
__global__ __launch_bounds__(256) void k_dec2(const u16* __restrict__ h,
                                              const float* __restrict__ W,
                                              const float* __restrict__ b,
                                              float* __restrict__ out, int M) {
  __shared__ float Ws[1024];
  int t = threadIdx.x;
  for (int i = t; i < 1024; i += 256) Ws[i] = W[i];
  __syncthreads();
  int node = blockIdx.x * 4 + (t >> 6);
  int lane = t & 63;
  if (node >= M) return;
  const u16* hr = h + (size_t)node * 256;
  ushort4 v = *(const ushort4*)(hr + lane * 4);
  float f0 = bf2f(v.x), f1 = bf2f(v.y), f2v = bf2f(v.z), f3 = bf2f(v.w);
  float a[4];
  #pragma unroll
  for (int o = 0; o < 4; ++o) {
    const float* wr = Ws + o * 256 + lane * 4;
    a[o] = f0 * wr[0] + f1 * wr[1] + f2v * wr[2] + f3 * wr[3];
  }
  #pragma unroll
  for (int off = 32; off > 0; off >>= 1) {
    #pragma unroll
    for (int o = 0; o < 4; ++o) a[o] += __shfl_down(a[o], off, 64);
  }
  if (lane == 0) {
    #pragma unroll
    for (int o = 0; o < 4; ++o) out[(size_t)node * 4 + o] = a[o] + b[o];
  }
}

// ---------------- launch ----------------
extern "C" void kernel_launch(void* const* d_in, const int* in_sizes, int n_in,
                              void* d_out, int out_size, void* d_ws, size_t ws_size,
                              hipStream_t stream) {
  const float* x     = (const float*)d_in[0];
  const int*   ei    = (const int*)d_in[1];
  const float* encW1 = (const float*)d_in[2];
  const float* encb1 = (const float*)d_in[3];
  const float* encW2 = (const float*)d_in[4];
  const float* encb2 = (const float*)d_in[5];
  const float* Wl    = (const float*)d_in[6];
  const float* bl    = (const float*)d_in[7];
  const float* Wr    = (const float*)d_in[8];
  const float* gamma = (const float*)d_in[9];
  const float* beta  = (const float*)d_in[10];
  const float* decW1 = (const float*)d_in[11];
  const float* decb1 = (const float*)d_in[12];
  const float* decW2 = (const float*)d_in[13];
  const float* decb2 = (const float*)d_in[14];
  float* out = (float*)d_out;

  const int M = M_NODES, E = E_EDGES;
  char* p = (char*)d_ws;
  auto take = [&](size_t b) { char* r = p; p += (b + 255) & ~(size_t)255; return r; };
  u16* zA     = (u16*)take((size_t)M * 128 * 2);
  u16* zB     = (u16*)take((size_t)M * 128 * 2);
  u16* zP     = (u16*)take((size_t)M * 128 * 2);
  u16* mean   = (u16*)take((size_t)M * 128 * 2);
  u16* hbuf   = (u16*)take((size_t)M * 256 * 2);
  u16* Bpack  = (u16*)take((size_t)229376 * 2);
  int* cnt    = (int*)take((size_t)M * 4);
  int* bucket = (int*)take((size_t)M * BKT * 4);
  float* ssums = (float*)take(4 * 256 * 4);

  const int* srcp = ei;
  const int* dstp = ei + E;

  k_prep<<<896, 256, 0, stream>>>(encW2, Wl, Wr, decW1, Bpack);
  hipMemsetAsync(cnt, 0, (size_t)M * 4, stream);
  hipMemsetAsync(ssums, 0, 4 * 256 * 4, stream);
  k_place<<<(E + 255) / 256, 256, 0, stream>>>(srcp, dstp, cnt, bucket, E);

  const int GX = (M + 63) / 64;

  // encoder
  k_enc1<<<M / 8, 256, 0, stream>>>(x, encW1, encb1, hbuf, M);
  k_mfma_gemm<8, 0><<<dim3(GX, 1), 256, 0, stream>>>(
      hbuf, hbuf + 128, 256, Bpack, encb2, zA, 128, M, 0, nullptr);

  u16* cur = zA;
  u16* nxt = zB;
  for (int i = 0; i < 5; ++i) {
    if (i == 0) {
      k_agg<0><<<M / 4, 256, 0, stream>>>(cur, cnt, bucket, nullptr, nullptr, nullptr,
                                          mean, zP, M);
    } else {
      k_agg<1><<<M / 4, 256, 0, stream>>>(cur, cnt, bucket, ssums + (i - 1) * 256,
                                          gamma + (size_t)(i - 1) * 128,
                                          beta + (size_t)(i - 1) * 128, mean, zP, M);
    }
    const u16* A2 = (i == 0) ? cur : zP;
    if (i < 4) {
      k_mfma_gemm<8, 1><<<dim3(GX, 1), 256, 0, stream>>>(
          mean, A2, 128, Bpack + 32768 + i * 32768, bl + (size_t)i * 128,
          nxt, 128, M, 0, ssums + i * 256);
    } else {
      k_mfma_gemm<8, 0><<<dim3(GX, 1), 256, 0, stream>>>(
          mean, A2, 128, Bpack + 32768 + i * 32768, bl + (size_t)i * 128,
          nxt, 128, M, 0, nullptr);
    }
    u16* tswap = cur; cur = nxt; nxt = tswap;
  }

  // decoder
  k_mfma_gemm<4, 0><<<dim3(GX, 2), 256, 0, stream>>>(
      cur, cur + 64, 128, Bpack + 196608, decb1, hbuf, 256, M, 1, nullptr);
  k_dec2<<<(M + 3) / 4, 256, 0, stream>>>(hbuf, decW2, decb2, out, M);
}